// Round 5
// baseline (762.523 us; speedup 1.0000x reference)
//
#include <hip/hip_runtime.h>

typedef unsigned short u16;
typedef unsigned int u32;

#define N_ATOM   50000
#define M_NBR    12
#define A_FEA    128
#define NBR_FEA  64
#define KDIM     320
#define CDIM     256
#define ROWS     600000
#define RPB      48          // rows per block (= 4 atoms)
#define NBLK     12500       // 600000 / 48
#define KC       10          // K chunks of 32
#define EPSV     1e-5f
#define A_PITCH  656         // (320+8) bf16 * 2B, padded row pitch in bytes
#define GRID1    256         // persistent grid: 1 block/CU, 512 threads
#define BUFSZ    31744       // A-tile 48*656 = 31488 + mask 192, padded
#define MASK_OFF 31488

using frag  = __attribute__((ext_vector_type(8))) short;
using f32x4 = __attribute__((ext_vector_type(4))) float;

// ---- workspace layout (float offsets) ----
#define WS_SUM1      0        // 256 (gemm1 atomics / red1)
#define WS_SUMSQ1    256      // 256 (contiguous with SUM1)
#define WS_CNT       512
#define WS_SUM2      516      // 128
#define WS_SUMSQ2    644      // 128 (contiguous with SUM2)
#define WS_STATS_END 772
#define WS_SCALE1    1024     // fallback path only
#define WS_SHIFT1    1280
#define WS_NBR       2048                      // 50000*128 floats
#define WS_W_FOFF    (2048 + 6400000)          // swizzled W: 81920 u16 = 40960 floats
#define WS_P_FOFF    (2048 + 6400000 + 40960)  // per-block partials (fallback path)
#define WS_G_FOFF    (WS_P_FOFF + 6400000)     // H: u32[600000][128] f/k bf16 pairs = 307.2 MB
#define WS_NEED_BYTES 358572032ull

__device__ __forceinline__ u32 fbits(float f) { union { float f; u32 u; } v; v.f = f; return v.u; }
__device__ __forceinline__ float bits2f(u32 u) { union { u32 u; float f; } v; v.u = u; return v.f; }
// round-half-up bf16 pair pack: low16 = bf(a), high16 = bf(b)  (1 perm + 2 add)
__device__ __forceinline__ u32 pkbf(float a, float b) {
    return __builtin_amdgcn_perm(fbits(b) + 0x8000u, fbits(a) + 0x8000u, 0x07060302u);
}
__device__ __forceinline__ u16 f2bf1(float f) { return (u16)((fbits(f) + 0x8000u) >> 16); }
__device__ __forceinline__ float bf2f(u16 u) { return bits2f(((u32)u) << 16); }
// fast softplus: v_exp + v_log instead of log1pf libcall
__device__ __forceinline__ float softplusf(float x) {
    return fmaxf(x, 0.f) + __logf(1.f + __expf(-fabsf(x)));
}
// fast sigmoid: v_rcp instead of IEEE div sequence
__device__ __forceinline__ float sigmoidf(float x) {
    return __builtin_amdgcn_rcpf(1.f + __expf(-x));
}

// Swizzle W (320x256 row-major fp32) -> wsW[kk][n][32] fragment-major bf16 (RNE, one-time)
__global__ void swizzleW(const float* __restrict__ W, u16* __restrict__ wsW) {
    int g = blockIdx.x * 256 + threadIdx.x;
    if (g >= KDIM * CDIM) return;
    int k = g >> 8, n = g & 255;
    u32 u = fbits(W[g]);
    u32 r = u + 0x7fffu + ((u >> 16) & 1u);
    wsW[((k >> 5) * 256 + n) * 32 + (k & 31)] = (u16)(r >> 16);
}

// sum(mask) -> ws[WS_CNT]  (fallback path only)
__global__ __launch_bounds__(256) void mask_cnt(const float* __restrict__ mask, float* __restrict__ ws) {
    int t = blockIdx.x * 256 + threadIdx.x;
    float s = 0.f;
    if (t < 37500) {
        const float* p = mask + (size_t)t * 16;
        #pragma unroll
        for (int i = 0; i < 4; i++) {
            float4 v = *(const float4*)(p + i * 4);
            s += (v.x + v.y) + (v.z + v.w);
        }
    }
    #pragma unroll
    for (int d = 1; d < 64; d <<= 1) s += __shfl_xor(s, d, 64);
    __shared__ float r[4];
    int l = threadIdx.x & 63, w = threadIdx.x >> 6;
    if (l == 0) r[w] = s;
    __syncthreads();
    if (threadIdx.x == 0) atomicAdd(&ws[WS_CNT], r[0] + r[1] + r[2] + r[3]);
}

// ===================================================================================
// Pipelined MODE-1 GEMM, fully fused stats: 256 persistent blocks x 512 threads,
// 1 block/CU, __launch_bounds__(512,2). Per-tile column sums are accumulated in
// REGISTERS across the block's ~49 tiles (butterfly-shuffle leaves the total in all
// lanes), then ONE atomicAdd per column at kernel end -> red1 + P1 traffic gone.
// mask count accumulated alongside load_meta -> mask_cnt kernel gone.
// ===================================================================================
struct Meta {
    int   idx[3];
    float mg[3];
    float mnA, mnB;
    float mrow;
};
struct Data {
    float4 sv, gv[3], nva, nvb;
};

__device__ __forceinline__ void load_meta(Meta& M, const int* __restrict__ nbridx,
                                          const float* __restrict__ mask,
                                          int r0, int w, int l, int tid) {
    const int h32 = l >> 5;
    #pragma unroll
    for (int j = 0; j < 3; ++j) {
        int row = 6 * w + 2 * j + h32;
        M.idx[j] = nbridx[r0 + row];
        M.mg[j]  = mask[r0 + row];
    }
    M.mnA = mask[r0 + 6 * w + (l >> 4)];
    M.mnB = (l < 32) ? mask[r0 + 6 * w + 4 + (l >> 4)] : 0.f;
    M.mrow = (tid < 48) ? mask[r0 + tid] : 0.f;
}

__device__ __forceinline__ void load_data(Data& D, const Meta& M,
                                          const float* __restrict__ atom,
                                          const float* __restrict__ nbrf,
                                          int t, int w, int l) {
    const int c32 = l & 31;
    D.sv = *(const float4*)(atom + (size_t)(t * 4 + (w >> 1)) * 128 + c32 * 4);
    #pragma unroll
    for (int j = 0; j < 3; ++j)
        if (M.mg[j] != 0.f)
            D.gv[j] = *(const float4*)(atom + (size_t)M.idx[j] * 128 + c32 * 4);
    const float* nb = nbrf + (size_t)(t * RPB + 6 * w) * 64;
    if (M.mnA != 0.f) D.nva = *(const float4*)(nb + (l >> 4) * 64 + (l & 15) * 4);
    if (l < 32 && M.mnB != 0.f) D.nvb = *(const float4*)(nb + (4 + (l >> 4)) * 64 + (l & 15) * 4);
}

__device__ __forceinline__ void write_tile(const Data& D, const Meta& M, char* nb,
                                           int w, int l, int tid) {
    const int h32 = l >> 5, c32 = l & 31;
    {
        uint2 p; p.x = pkbf(D.sv.x, D.sv.y); p.y = pkbf(D.sv.z, D.sv.w);
        #pragma unroll
        for (int jj = 0; jj < 3; ++jj)
            *(uint2*)(nb + (6 * w + 3 * h32 + jj) * A_PITCH + c32 * 8) = p;
    }
    #pragma unroll
    for (int j = 0; j < 3; ++j) {
        int row = 6 * w + 2 * j + h32;
        uint2 g; g.x = 0u; g.y = 0u;
        if (M.mg[j] != 0.f) { g.x = pkbf(D.gv[j].x, D.gv[j].y); g.y = pkbf(D.gv[j].z, D.gv[j].w); }
        *(uint2*)(nb + row * A_PITCH + 256 + c32 * 8) = g;
    }
    {
        int rowA = 6 * w + (l >> 4);
        uint2 na; na.x = 0u; na.y = 0u;
        if (M.mnA != 0.f) { na.x = pkbf(D.nva.x, D.nva.y); na.y = pkbf(D.nva.z, D.nva.w); }
        *(uint2*)(nb + rowA * A_PITCH + 512 + (l & 15) * 8) = na;
    }
    if (l < 32) {
        int rowB = 6 * w + 4 + (l >> 4);
        uint2 nv; nv.x = 0u; nv.y = 0u;
        if (M.mnB != 0.f) { nv.x = pkbf(D.nvb.x, D.nvb.y); nv.y = pkbf(D.nvb.z, D.nvb.w); }
        *(uint2*)(nb + rowB * A_PITCH + 512 + (l & 15) * 8) = nv;
    }
    if (tid < 48) *(float*)(nb + MASK_OFF + tid * 4) = M.mrow;
}

__global__ __launch_bounds__(512, 2) void gemm1_pipe(
    const float* __restrict__ atom, const float* __restrict__ nbrf,
    const int* __restrict__ nbridx, const float* __restrict__ mask,
    const u16* __restrict__ wsW, float* __restrict__ ws)
{
    __shared__ __align__(16) char smem[2 * BUFSZ];
    const int tid = threadIdx.x;
    const int w = tid >> 6, l = tid & 63, l15 = l & 15, l4 = l >> 4;
    u32* __restrict__ Hbase = (u32*)(ws + WS_G_FOFF);

    // resident B fragments: cols 16w+l15 (cf0) and 128+16w+l15 (cf1), all 10 kk
    frag Bf[KC][2];
    #pragma unroll
    for (int kk = 0; kk < KC; ++kk)
        #pragma unroll
        for (int cf = 0; cf < 2; ++cf)
            Bf[kk][cf] = *(const frag*)((const char*)wsW +
                ((size_t)(kk * 256 + cf * 128 + 16 * w + l15) * 64 + l4 * 16));

    Meta M; Data D;
    float cnt_acc = 0.f;
    float sacc[2] = {0.f, 0.f}, qacc[2] = {0.f, 0.f};
    const int t0 = blockIdx.x;

    // ---- prologue: stage tile t0 into buf0 ----
    load_meta(M, nbridx, mask, t0 * RPB, w, l, tid);
    cnt_acc += M.mrow;
    load_data(D, M, atom, nbrf, t0, w, l);
    write_tile(D, M, smem, w, l, tid);
    if (t0 + GRID1 < NBLK) {
        load_meta(M, nbridx, mask, (t0 + GRID1) * RPB, w, l, tid);
        cnt_acc += M.mrow;
    }
    __syncthreads();

    int cur = 0;
    for (int t = t0; t < NBLK; t += GRID1) {
        const int tn = t + GRID1;
        const bool hasNext = (tn < NBLK);
        char* bufc = smem + cur * BUFSZ;
        char* bufn = smem + (cur ^ 1) * BUFSZ;

        // issue next-tile data loads; latency hides under the K-loop (no VMEM below)
        if (hasNext) load_data(D, M, atom, nbrf, tn, w, l);

        // ---- K-loop: pure LDS + MFMA ----
        f32x4 acc[3][2];
        #pragma unroll
        for (int rf = 0; rf < 3; ++rf) {
            acc[rf][0] = (f32x4){0.f, 0.f, 0.f, 0.f};
            acc[rf][1] = (f32x4){0.f, 0.f, 0.f, 0.f};
        }
        const char* Ac = bufc + l15 * A_PITCH + l4 * 16;
        #pragma unroll
        for (int kk = 0; kk < KC; ++kk) {
            frag a[3];
            #pragma unroll
            for (int rf = 0; rf < 3; ++rf)
                a[rf] = *(const frag*)(Ac + rf * 16 * A_PITCH + kk * 64);
            #pragma unroll
            for (int rf = 0; rf < 3; ++rf) {
                acc[rf][0] = __builtin_amdgcn_mfma_f32_16x16x32_bf16(a[rf], Bf[kk][0], acc[rf][0], 0, 0, 0);
                acc[rf][1] = __builtin_amdgcn_mfma_f32_16x16x32_bf16(a[rf], Bf[kk][1], acc[rf][1], 0, 0, 0);
            }
        }

        // ---- epilogue: masked stats (register accumulate) + H store ----
        f32x4 mm[3];
        #pragma unroll
        for (int rf = 0; rf < 3; ++rf)
            mm[rf] = *(const f32x4*)(bufc + MASK_OFF + (rf * 16 + l4 * 4) * 4);
        #pragma unroll
        for (int cf = 0; cf < 2; ++cf) {
            float s = 0.f, q = 0.f;
            #pragma unroll
            for (int rf = 0; rf < 3; ++rf)
                #pragma unroll
                for (int rg = 0; rg < 4; ++rg) {
                    float mv = mm[rf][rg];
                    float v = acc[rf][cf][rg];
                    s += mv * v; q += mv * v * v;
                }
            s += __shfl_xor(s, 16, 64); s += __shfl_xor(s, 32, 64);
            q += __shfl_xor(q, 16, 64); q += __shfl_xor(q, 32, 64);
            sacc[cf] += s;      // butterfly leaves total in all lanes
            qacc[cf] += q;
        }
        {
            u32* H = Hbase + (size_t)t * (RPB * 128) + 16 * w + l15;
            #pragma unroll
            for (int rf = 0; rf < 3; ++rf)
                #pragma unroll
                for (int rg = 0; rg < 4; ++rg) {
                    const int row = rf * 16 + l4 * 4 + rg;
                    if (mm[rf][rg] != 0.f)
                        H[(size_t)row * 128] = pkbf(acc[rf][0][rg], acc[rf][1][rg]);
                }
        }

        // ---- pack + write next tile; prefetch meta for tn+GRID1 ----
        if (hasNext) write_tile(D, M, bufn, w, l, tid);
        if (tn + GRID1 < NBLK) {
            load_meta(M, nbridx, mask, (tn + GRID1) * RPB, w, l, tid);
            cnt_acc += M.mrow;
        }
        __syncthreads();   // drains staged loads (issued ~1 K-loop ago) + H stores
        cur ^= 1;
    }

    // ---- end-of-block: fused red1 + mask_cnt ----
    if (l4 == 0) {
        #pragma unroll
        for (int cf = 0; cf < 2; ++cf) {
            int col = cf * 128 + 16 * w + l15;
            atomicAdd(&ws[WS_SUM1 + col],   sacc[cf]);
            atomicAdd(&ws[WS_SUMSQ1 + col], qacc[cf]);
        }
    }
    if (w == 0) {   // only wave 0 (tid<48) holds nonzero cnt contributions
        float c = cnt_acc;
        #pragma unroll
        for (int d = 1; d < 64; d <<= 1) c += __shfl_xor(c, d, 64);
        if (l == 0) atomicAdd(&ws[WS_CNT], c);
    }
}

// Fallback path (small workspace): original one-shot kernel, MODE 0 (stats) / MODE 2 (recompute+gate)
template <int MODE>
__global__ __launch_bounds__(256, 3) void gemm_pass(
    const float* __restrict__ atom, const float* __restrict__ nbrf,
    const int* __restrict__ nbridx, const float* __restrict__ mask,
    const u16* __restrict__ wsW, float* __restrict__ ws)
{
    __shared__ __align__(16) char smem[RPB * A_PITCH];   // A-tile; MODE2 reuses as g16
    __shared__ float m_lds[RPB];
    __shared__ int   idx_lds[RPB];
    __shared__ float red[(MODE == 2) ? 4 : 1][128];

    const int tid = threadIdx.x;
    const int w = tid >> 6, l = tid & 63, l15 = l & 15, l4 = l >> 4;
    const int h32 = l >> 5, c32 = l & 31;
    const int blk = blockIdx.x;
    const int r0 = blk * RPB;
    float* __restrict__ P = ws + WS_P_FOFF;

    if (tid < RPB) {
        m_lds[tid] = mask[r0 + tid];
        idx_lds[tid] = nbridx[r0 + tid];
    }
    __syncthreads();

    {
        float4 sv = *(const float4*)(atom + (size_t)(blk * 4 + w) * 128 + c32 * 4);
        uint2 p; p.x = pkbf(sv.x, sv.y); p.y = pkbf(sv.z, sv.w);
        #pragma unroll
        for (int jj = 0; jj < 6; ++jj) {
            int row = 12 * w + 6 * h32 + jj;
            *(uint2*)(smem + row * A_PITCH + c32 * 8) = p;
        }
    }
    {
        float4 v[6]; float mrow[6];
        #pragma unroll
        for (int i = 0; i < 6; ++i) {
            int row = 12 * w + 2 * i + h32;
            mrow[i] = m_lds[row];
            if (mrow[i] != 0.f)
                v[i] = *(const float4*)(atom + (size_t)idx_lds[row] * 128 + c32 * 4);
        }
        #pragma unroll
        for (int i = 0; i < 6; ++i) {
            int row = 12 * w + 2 * i + h32;
            uint2 p; p.x = 0u; p.y = 0u;
            if (mrow[i] != 0.f) { p.x = pkbf(v[i].x, v[i].y); p.y = pkbf(v[i].z, v[i].w); }
            *(uint2*)(smem + row * A_PITCH + 256 + c32 * 8) = p;
        }
    }
    {
        const float* nf = nbrf + (size_t)(r0 + 12 * w) * 64;
        float4 v[3]; float mrow[3]; int rowv[3], cv[3];
        #pragma unroll
        for (int i = 0; i < 3; ++i) {
            int g = i * 64 + l;
            rowv[i] = 12 * w + (g >> 4);
            cv[i] = g & 15;
            mrow[i] = m_lds[rowv[i]];
            if (mrow[i] != 0.f) v[i] = *(const float4*)(nf + g * 4);
        }
        #pragma unroll
        for (int i = 0; i < 3; ++i) {
            uint2 p; p.x = 0u; p.y = 0u;
            if (mrow[i] != 0.f) { p.x = pkbf(v[i].x, v[i].y); p.y = pkbf(v[i].z, v[i].w); }
            *(uint2*)(smem + rowv[i] * A_PITCH + 512 + cv[i] * 8) = p;
        }
    }
    __syncthreads();

    f32x4 acc[3][4];
    #pragma unroll
    for (int rf = 0; rf < 3; rf++)
        #pragma unroll
        for (int cf = 0; cf < 4; cf++)
            acc[rf][cf] = (f32x4){0.f, 0.f, 0.f, 0.f};

    const char* Ab = smem + l15 * A_PITCH + l4 * 16;
    const char* Bb = (const char*)wsW + ((size_t)w * 2048 + l15 * 64 + l4 * 16);
    frag bcur[4], bnext[4];
    #pragma unroll
    for (int cf = 0; cf < 4; ++cf)
        bcur[cf] = *(const frag*)(Bb + cf * 1024 + (cf >= 2 ? 6144 : 0));
    #pragma unroll
    for (int kk = 0; kk < KC; ++kk) {
        if (kk < KC - 1) {
            const char* Bn = Bb + (kk + 1) * 16384;
            #pragma unroll
            for (int cf = 0; cf < 4; ++cf)
                bnext[cf] = *(const frag*)(Bn + cf * 1024 + (cf >= 2 ? 6144 : 0));
        }
        frag a[3];
        #pragma unroll
        for (int rf = 0; rf < 3; rf++)
            a[rf] = *(const frag*)(Ab + rf * 16 * A_PITCH + kk * 64);
        #pragma unroll
        for (int rf = 0; rf < 3; rf++)
            #pragma unroll
            for (int cf = 0; cf < 4; cf++)
                acc[rf][cf] = __builtin_amdgcn_mfma_f32_16x16x32_bf16(a[rf], bcur[cf], acc[rf][cf], 0, 0, 0);
        #pragma unroll
        for (int cf = 0; cf < 4; ++cf) bcur[cf] = bnext[cf];
    }

    if constexpr (MODE == 0) {
        #pragma unroll
        for (int cf = 0; cf < 4; cf++) {
            float s = 0.f, q = 0.f;
            #pragma unroll
            for (int rf = 0; rf < 3; rf++)
                #pragma unroll
                for (int rg = 0; rg < 4; rg++) {
                    int row = rf * 16 + l4 * 4 + rg;
                    float mv = m_lds[row];
                    float v = acc[rf][cf][rg];
                    s += mv * v; q += mv * v * v;
                }
            s += __shfl_xor(s, 16, 64); s += __shfl_xor(s, 32, 64);
            q += __shfl_xor(q, 16, 64); q += __shfl_xor(q, 32, 64);
            if (l4 == 0) {
                int col = w * 32 + cf * 16 + (cf >= 2 ? 96 : 0) + l15;
                P[(size_t)blk * 512 + col]       = s;
                P[(size_t)blk * 512 + 256 + col] = q;
            }
        }
    } else {
        __syncthreads();
        u16* g16 = (u16*)smem;
        #pragma unroll
        for (int cf = 0; cf < 4; cf++) {
            int col = w * 32 + cf * 16 + (cf >= 2 ? 96 : 0) + l15;
            float sc = ws[WS_SCALE1 + col];
            float sh = ws[WS_SHIFT1 + col];
            #pragma unroll
            for (int rf = 0; rf < 3; rf++)
                #pragma unroll
                for (int rg = 0; rg < 4; rg++) {
                    int row = rf * 16 + l4 * 4 + rg;
                    g16[row * 256 + col] = f2bf1(acc[rf][cf][rg] * sc + sh);
                }
        }
        __syncthreads();
        int h = tid >> 7;
        int c = tid & 127;
        float ns0 = 0.f, ns1 = 0.f;
        #pragma unroll
        for (int la2 = 0; la2 < 2; la2++) {
            int la = h * 2 + la2;
            float a_ns = 0.f;
            #pragma unroll
            for (int j = 0; j < 12; j++) {
                int row = la * 12 + j;
                float f = bf2f(g16[row * 256 + c]);
                float k = bf2f(g16[row * 256 + 128 + c]);
                a_ns += m_lds[row] * sigmoidf(f) * softplusf(k);
            }
            ws[WS_NBR + (blk * 4 + la) * 128 + c] = a_ns;
            if (la2 == 0) ns0 = a_ns; else ns1 = a_ns;
        }
        red[h][c]     = ns0 + ns1;
        red[2 + h][c] = ns0 * ns0 + ns1 * ns1;
        __syncthreads();
        if (tid < 128) {
            P[(size_t)blk * 256 + tid]       = red[0][tid] + red[1][tid];
            P[(size_t)blk * 256 + 128 + tid] = red[2][tid] + red[3][tid];
        }
    }
}

// path-A pass 2: load paired H, inline-finalize1, BN1 in f32 + gate + reduce,
// direct atomics into SUM2/SUMSQ2 (red2 fused).
__global__ __launch_bounds__(256) void pass2_gate(
    const float* __restrict__ ws_ro, const float* __restrict__ mask,
    const float* __restrict__ g1, const float* __restrict__ b1,
    float* __restrict__ ws)
{
    __shared__ float m_lds[RPB];
    __shared__ float red[4][128];

    const int tid = threadIdx.x;
    const int blk = blockIdx.x;
    const int h = tid >> 7, c = tid & 127;

    if (tid < RPB) m_lds[tid] = mask[blk * RPB + tid];

    // inline finalize1 (SUM1/SUMSQ1/CNT complete after gemm1_pipe)
    const float rc = 1.f / ws_ro[WS_CNT];
    float mf = ws_ro[WS_SUM1 + c] * rc;
    float vf = ws_ro[WS_SUMSQ1 + c] * rc - mf * mf;
    const float scf = g1[c] * rsqrtf(vf + EPSV);
    const float shf = b1[c] - mf * scf;
    float mk = ws_ro[WS_SUM1 + 128 + c] * rc;
    float vk = ws_ro[WS_SUMSQ1 + 128 + c] * rc - mk * mk;
    const float sck = g1[128 + c] * rsqrtf(vk + EPSV);
    const float shk = b1[128 + c] - mk * sck;
    __syncthreads();

    const u32* Hb = (const u32*)(ws_ro + WS_G_FOFF) + (size_t)blk * (RPB * 128) + c;

    float ns0 = 0.f, ns1 = 0.f;
    #pragma unroll
    for (int la2 = 0; la2 < 2; la2++) {
        const int la = h * 2 + la2;
        u32 v[12]; float mv[12];
        #pragma unroll
        for (int j = 0; j < 12; j++) {
            mv[j] = m_lds[la * 12 + j];
            if (mv[j] != 0.f) v[j] = Hb[(size_t)(la * 12 + j) * 128];
        }
        float a_ns = 0.f;
        #pragma unroll
        for (int j = 0; j < 12; j++) {
            if (mv[j] != 0.f) {
                const u32 u = v[j];
                float f = bits2f(u << 16)         * scf + shf;
                float k = bits2f(u & 0xffff0000u) * sck + shk;
                float sg = __builtin_amdgcn_rcpf(1.f + __expf(-f));
                float sp = fmaxf(k, 0.f) + __logf(1.f + __expf(-fabsf(k)));
                a_ns += sg * sp;
            }
        }
        ws[WS_NBR + (blk * 4 + la) * 128 + c] = a_ns;
        if (la2 == 0) ns0 = a_ns; else ns1 = a_ns;
    }
    red[h][c]     = ns0 + ns1;
    red[2 + h][c] = ns0 * ns0 + ns1 * ns1;
    __syncthreads();
    if (tid < 128) {
        atomicAdd(&ws[WS_SUM2 + tid],   red[0][tid] + red[1][tid]);
        atomicAdd(&ws[WS_SUMSQ2 + tid], red[2][tid] + red[3][tid]);
    }
}

// reduce P1[12500][512] over blocks -> ws[WS_SUM1..] ; grid 250 (fallback path)
__global__ __launch_bounds__(256) void red1(const float* __restrict__ ws_ro, float* __restrict__ ws) {
    const float* P = ws_ro + WS_P_FOFF;
    int c = (blockIdx.x & 1) * 256 + threadIdx.x;
    int s = blockIdx.x >> 1;
    const float* p = P + (size_t)s * 100 * 512 + c;
    float a = 0.f;
    #pragma unroll 4
    for (int r = 0; r < 100; r++) a += p[(size_t)r * 512];
    atomicAdd(&ws[WS_SUM1 + c], a);
}

// reduce P2[12500][256] over blocks -> ws[WS_SUM2..] ; grid 125 (fallback path)
__global__ __launch_bounds__(256) void red2(const float* __restrict__ ws_ro, float* __restrict__ ws) {
    const float* P = ws_ro + WS_P_FOFF;
    int s = blockIdx.x;
    const float* p = P + (size_t)s * 100 * 256 + threadIdx.x;
    float a = 0.f;
    #pragma unroll 4
    for (int r = 0; r < 100; r++) a += p[(size_t)r * 256];
    atomicAdd(&ws[WS_SUM2 + threadIdx.x], a);
}

// fallback path only (bigws inlines this into pass2_gate)
__global__ void finalize1(float* __restrict__ ws, const float* __restrict__ g1, const float* __restrict__ b1) {
    int c = threadIdx.x;  // 256
    float cnt = ws[WS_CNT];
    float mean = ws[WS_SUM1 + c] / cnt;
    float var  = ws[WS_SUMSQ1 + c] / cnt - mean * mean;
    float sc = g1[c] * rsqrtf(var + EPSV);
    ws[WS_SCALE1 + c] = sc;
    ws[WS_SHIFT1 + c] = b1[c] - mean * sc;
}

// out_kernel with inline finalize2 (both paths)
__global__ __launch_bounds__(256) void out_kernel(
    const float* __restrict__ atom, const float* __restrict__ ws,
    const float* __restrict__ g2, const float* __restrict__ b2,
    float* __restrict__ out)
{
    int g = blockIdx.x * 256 + threadIdx.x;
    if (g >= N_ATOM * 32) return;
    int i = g >> 5, c4 = (g & 31) * 4;
    const float inv = 1.f / (float)N_ATOM;
    float4 s2  = *(const float4*)(ws + WS_SUM2 + c4);
    float4 q2  = *(const float4*)(ws + WS_SUMSQ2 + c4);
    float4 g2v = *(const float4*)(g2 + c4);
    float4 b2v = *(const float4*)(b2 + c4);
    float4 sc, sh;
    { float m = s2.x * inv; sc.x = g2v.x * rsqrtf(q2.x * inv - m * m + EPSV); sh.x = b2v.x - m * sc.x; }
    { float m = s2.y * inv; sc.y = g2v.y * rsqrtf(q2.y * inv - m * m + EPSV); sh.y = b2v.y - m * sc.y; }
    { float m = s2.z * inv; sc.z = g2v.z * rsqrtf(q2.z * inv - m * m + EPSV); sh.z = b2v.z - m * sc.z; }
    { float m = s2.w * inv; sc.w = g2v.w * rsqrtf(q2.w * inv - m * m + EPSV); sh.w = b2v.w - m * sc.w; }
    float4 av = *(const float4*)(atom + i * 128 + c4);
    float4 nv = *(const float4*)(ws + WS_NBR + i * 128 + c4);
    float4 ov;
    ov.x = softplusf(av.x + nv.x * sc.x + sh.x);
    ov.y = softplusf(av.y + nv.y * sc.y + sh.y);
    ov.z = softplusf(av.z + nv.z * sc.z + sh.z);
    ov.w = softplusf(av.w + nv.w * sc.w + sh.w);
    *(float4*)(out + i * 128 + c4) = ov;
}

extern "C" void kernel_launch(void* const* d_in, const int* in_sizes, int n_in,
                              void* d_out, int out_size, void* d_ws, size_t ws_size,
                              hipStream_t stream) {
    (void)in_sizes; (void)n_in; (void)out_size;
    const float* atom = (const float*)d_in[0];
    const float* nbrf = (const float*)d_in[1];
    const int*   nidx = (const int*)d_in[2];
    const float* mask = (const float*)d_in[3];
    const float* W    = (const float*)d_in[4];
    // d_in[5] = b_fc: zeros AND cancels exactly through BN1 for masked rows; unused
    const float* g1 = (const float*)d_in[6];
    const float* b1 = (const float*)d_in[7];
    const float* g2 = (const float*)d_in[8];
    const float* b2 = (const float*)d_in[9];
    float* ws  = (float*)d_ws;
    u16*  wsW  = (u16*)((char*)d_ws + (size_t)WS_W_FOFF * 4);
    float* out = (float*)d_out;
    const bool bigws = (ws_size >= WS_NEED_BYTES);

    hipMemsetAsync(d_ws, 0, WS_STATS_END * 4, stream);
    swizzleW<<<(KDIM * CDIM + 255) / 256, 256, 0, stream>>>(W, wsW);
    if (bigws) {
        gemm1_pipe<<<GRID1, 512, 0, stream>>>(atom, nbrf, nidx, mask, wsW, ws);
        pass2_gate<<<NBLK, 256, 0, stream>>>(ws, mask, g1, b1, ws);
    } else {
        mask_cnt<<<147, 256, 0, stream>>>(mask, ws);
        gemm_pass<0><<<NBLK, 256, 0, stream>>>(atom, nbrf, nidx, mask, wsW, ws);
        red1<<<250, 256, 0, stream>>>(ws, ws);
        finalize1<<<1, 256, 0, stream>>>(ws, g1, b1);
        gemm_pass<2><<<NBLK, 256, 0, stream>>>(atom, nbrf, nidx, mask, wsW, ws);
        red2<<<125, 256, 0, stream>>>(ws, ws);
    }
    out_kernel<<<(N_ATOM * 32 + 255) / 256, 256, 0, stream>>>(atom, ws, g2, b2, out);
}

// Round 6
// 416.628 us; speedup vs baseline: 1.8302x; 1.8302x over previous
//
#include <hip/hip_runtime.h>

typedef unsigned short u16;
typedef unsigned int u32;

#define N_ATOM   50000
#define M_NBR    12
#define A_FEA    128
#define NBR_FEA  64
#define KDIM     320
#define CDIM     256
#define ROWS     600000
#define RPB      48          // rows per block (= 4 atoms)
#define NBLK     12500       // 600000 / 48
#define KC       10          // K chunks of 32
#define EPSV     1e-5f
#define A_PITCH  656         // (320+8) bf16 * 2B, padded row pitch in bytes
#define GRID1    256         // persistent grid: 1 block/CU, 512 threads
#define BUFSZ    31744       // A-tile 48*656 = 31488 + mask 192, padded
#define MASK_OFF 31488

using frag  = __attribute__((ext_vector_type(8))) short;
using f32x4 = __attribute__((ext_vector_type(4))) float;

// ---- workspace layout (float offsets) ----
#define WS_SUM1      0        // 256 (gemm1 atomics / red1)
#define WS_SUMSQ1    256      // 256 (contiguous with SUM1)
#define WS_CNT       512
#define WS_SUM2      516      // 128
#define WS_SUMSQ2    644      // 128 (contiguous with SUM2)
#define WS_STATS_END 772
#define WS_SCALE1    1024     // fallback path only
#define WS_SHIFT1    1280
#define WS_NBR       2048                      // 50000*128 floats
#define WS_W_FOFF    (2048 + 6400000)          // swizzled W: 81920 u16 = 40960 floats
#define WS_P_FOFF    (2048 + 6400000 + 40960)  // per-block partials: p2 12500*256 (+ fallback p1)
#define WS_G_FOFF    (WS_P_FOFF + 6400000)     // H: u32[600000][128] f/k bf16 pairs = 307.2 MB
#define WS_NEED_BYTES 358572032ull

__device__ __forceinline__ u32 fbits(float f) { union { float f; u32 u; } v; v.f = f; return v.u; }
__device__ __forceinline__ float bits2f(u32 u) { union { u32 u; float f; } v; v.u = u; return v.f; }
// round-half-up bf16 pair pack: low16 = bf(a), high16 = bf(b)  (1 perm + 2 add)
__device__ __forceinline__ u32 pkbf(float a, float b) {
    return __builtin_amdgcn_perm(fbits(b) + 0x8000u, fbits(a) + 0x8000u, 0x07060302u);
}
__device__ __forceinline__ u16 f2bf1(float f) { return (u16)((fbits(f) + 0x8000u) >> 16); }
__device__ __forceinline__ float bf2f(u16 u) { return bits2f(((u32)u) << 16); }
// fast softplus: v_exp + v_log instead of log1pf libcall
__device__ __forceinline__ float softplusf(float x) {
    return fmaxf(x, 0.f) + __logf(1.f + __expf(-fabsf(x)));
}
// fast sigmoid: v_rcp instead of IEEE div sequence
__device__ __forceinline__ float sigmoidf(float x) {
    return __builtin_amdgcn_rcpf(1.f + __expf(-x));
}

// Swizzle W (320x256 row-major fp32) -> wsW[kk][n][32] fragment-major bf16 (RNE, one-time)
__global__ void swizzleW(const float* __restrict__ W, u16* __restrict__ wsW) {
    int g = blockIdx.x * 256 + threadIdx.x;
    if (g >= KDIM * CDIM) return;
    int k = g >> 8, n = g & 255;
    u32 u = fbits(W[g]);
    u32 r = u + 0x7fffu + ((u >> 16) & 1u);
    wsW[((k >> 5) * 256 + n) * 32 + (k & 31)] = (u16)(r >> 16);
}

// sum(mask) -> ws[WS_CNT]  (fallback path only)
__global__ __launch_bounds__(256) void mask_cnt(const float* __restrict__ mask, float* __restrict__ ws) {
    int t = blockIdx.x * 256 + threadIdx.x;
    float s = 0.f;
    if (t < 37500) {
        const float* p = mask + (size_t)t * 16;
        #pragma unroll
        for (int i = 0; i < 4; i++) {
            float4 v = *(const float4*)(p + i * 4);
            s += (v.x + v.y) + (v.z + v.w);
        }
    }
    #pragma unroll
    for (int d = 1; d < 64; d <<= 1) s += __shfl_xor(s, d, 64);
    __shared__ float r[4];
    int l = threadIdx.x & 63, w = threadIdx.x >> 6;
    if (l == 0) r[w] = s;
    __syncthreads();
    if (threadIdx.x == 0) atomicAdd(&ws[WS_CNT], r[0] + r[1] + r[2] + r[3]);
}

// ===================================================================================
// Pipelined MODE-1 GEMM, fused stats (red1 + mask_cnt): 256 persistent blocks x 512
// threads, 1 block/CU. Per-tile column sums accumulate in registers across the
// block's ~49 tiles; ONE atomicAdd per column at kernel end (65K atomics, trivial).
// ===================================================================================
struct Meta {
    int   idx[3];
    float mg[3];
    float mnA, mnB;
    float mrow;
};
struct Data {
    float4 sv, gv[3], nva, nvb;
};

__device__ __forceinline__ void load_meta(Meta& M, const int* __restrict__ nbridx,
                                          const float* __restrict__ mask,
                                          int r0, int w, int l, int tid) {
    const int h32 = l >> 5;
    #pragma unroll
    for (int j = 0; j < 3; ++j) {
        int row = 6 * w + 2 * j + h32;
        M.idx[j] = nbridx[r0 + row];
        M.mg[j]  = mask[r0 + row];
    }
    M.mnA = mask[r0 + 6 * w + (l >> 4)];
    M.mnB = (l < 32) ? mask[r0 + 6 * w + 4 + (l >> 4)] : 0.f;
    M.mrow = (tid < 48) ? mask[r0 + tid] : 0.f;
}

__device__ __forceinline__ void load_data(Data& D, const Meta& M,
                                          const float* __restrict__ atom,
                                          const float* __restrict__ nbrf,
                                          int t, int w, int l) {
    const int c32 = l & 31;
    D.sv = *(const float4*)(atom + (size_t)(t * 4 + (w >> 1)) * 128 + c32 * 4);
    #pragma unroll
    for (int j = 0; j < 3; ++j)
        if (M.mg[j] != 0.f)
            D.gv[j] = *(const float4*)(atom + (size_t)M.idx[j] * 128 + c32 * 4);
    const float* nb = nbrf + (size_t)(t * RPB + 6 * w) * 64;
    if (M.mnA != 0.f) D.nva = *(const float4*)(nb + (l >> 4) * 64 + (l & 15) * 4);
    if (l < 32 && M.mnB != 0.f) D.nvb = *(const float4*)(nb + (4 + (l >> 4)) * 64 + (l & 15) * 4);
}

__device__ __forceinline__ void write_tile(const Data& D, const Meta& M, char* nb,
                                           int w, int l, int tid) {
    const int h32 = l >> 5, c32 = l & 31;
    {
        uint2 p; p.x = pkbf(D.sv.x, D.sv.y); p.y = pkbf(D.sv.z, D.sv.w);
        #pragma unroll
        for (int jj = 0; jj < 3; ++jj)
            *(uint2*)(nb + (6 * w + 3 * h32 + jj) * A_PITCH + c32 * 8) = p;
    }
    #pragma unroll
    for (int j = 0; j < 3; ++j) {
        int row = 6 * w + 2 * j + h32;
        uint2 g; g.x = 0u; g.y = 0u;
        if (M.mg[j] != 0.f) { g.x = pkbf(D.gv[j].x, D.gv[j].y); g.y = pkbf(D.gv[j].z, D.gv[j].w); }
        *(uint2*)(nb + row * A_PITCH + 256 + c32 * 8) = g;
    }
    {
        int rowA = 6 * w + (l >> 4);
        uint2 na; na.x = 0u; na.y = 0u;
        if (M.mnA != 0.f) { na.x = pkbf(D.nva.x, D.nva.y); na.y = pkbf(D.nva.z, D.nva.w); }
        *(uint2*)(nb + rowA * A_PITCH + 512 + (l & 15) * 8) = na;
    }
    if (l < 32) {
        int rowB = 6 * w + 4 + (l >> 4);
        uint2 nv; nv.x = 0u; nv.y = 0u;
        if (M.mnB != 0.f) { nv.x = pkbf(D.nvb.x, D.nvb.y); nv.y = pkbf(D.nvb.z, D.nvb.w); }
        *(uint2*)(nb + rowB * A_PITCH + 512 + (l & 15) * 8) = nv;
    }
    if (tid < 48) *(float*)(nb + MASK_OFF + tid * 4) = M.mrow;
}

__global__ __launch_bounds__(512, 2) void gemm1_pipe(
    const float* __restrict__ atom, const float* __restrict__ nbrf,
    const int* __restrict__ nbridx, const float* __restrict__ mask,
    const u16* __restrict__ wsW, float* __restrict__ ws)
{
    __shared__ __align__(16) char smem[2 * BUFSZ];
    const int tid = threadIdx.x;
    const int w = tid >> 6, l = tid & 63, l15 = l & 15, l4 = l >> 4;
    u32* __restrict__ Hbase = (u32*)(ws + WS_G_FOFF);

    // resident B fragments: cols 16w+l15 (cf0) and 128+16w+l15 (cf1), all 10 kk
    frag Bf[KC][2];
    #pragma unroll
    for (int kk = 0; kk < KC; ++kk)
        #pragma unroll
        for (int cf = 0; cf < 2; ++cf)
            Bf[kk][cf] = *(const frag*)((const char*)wsW +
                ((size_t)(kk * 256 + cf * 128 + 16 * w + l15) * 64 + l4 * 16));

    Meta M; Data D;
    float cnt_acc = 0.f;
    float sacc[2] = {0.f, 0.f}, qacc[2] = {0.f, 0.f};
    const int t0 = blockIdx.x;

    // ---- prologue: stage tile t0 into buf0 ----
    load_meta(M, nbridx, mask, t0 * RPB, w, l, tid);
    cnt_acc += M.mrow;
    load_data(D, M, atom, nbrf, t0, w, l);
    write_tile(D, M, smem, w, l, tid);
    if (t0 + GRID1 < NBLK) {
        load_meta(M, nbridx, mask, (t0 + GRID1) * RPB, w, l, tid);
        cnt_acc += M.mrow;
    }
    __syncthreads();

    int cur = 0;
    for (int t = t0; t < NBLK; t += GRID1) {
        const int tn = t + GRID1;
        const bool hasNext = (tn < NBLK);
        char* bufc = smem + cur * BUFSZ;
        char* bufn = smem + (cur ^ 1) * BUFSZ;

        // issue next-tile data loads; latency hides under the K-loop (no VMEM below)
        if (hasNext) load_data(D, M, atom, nbrf, tn, w, l);

        // ---- K-loop: pure LDS + MFMA ----
        f32x4 acc[3][2];
        #pragma unroll
        for (int rf = 0; rf < 3; ++rf) {
            acc[rf][0] = (f32x4){0.f, 0.f, 0.f, 0.f};
            acc[rf][1] = (f32x4){0.f, 0.f, 0.f, 0.f};
        }
        const char* Ac = bufc + l15 * A_PITCH + l4 * 16;
        #pragma unroll
        for (int kk = 0; kk < KC; ++kk) {
            frag a[3];
            #pragma unroll
            for (int rf = 0; rf < 3; ++rf)
                a[rf] = *(const frag*)(Ac + rf * 16 * A_PITCH + kk * 64);
            #pragma unroll
            for (int rf = 0; rf < 3; ++rf) {
                acc[rf][0] = __builtin_amdgcn_mfma_f32_16x16x32_bf16(a[rf], Bf[kk][0], acc[rf][0], 0, 0, 0);
                acc[rf][1] = __builtin_amdgcn_mfma_f32_16x16x32_bf16(a[rf], Bf[kk][1], acc[rf][1], 0, 0, 0);
            }
        }

        // ---- epilogue: masked stats (register accumulate) + H store ----
        f32x4 mm[3];
        #pragma unroll
        for (int rf = 0; rf < 3; ++rf)
            mm[rf] = *(const f32x4*)(bufc + MASK_OFF + (rf * 16 + l4 * 4) * 4);
        #pragma unroll
        for (int cf = 0; cf < 2; ++cf) {
            float s = 0.f, q = 0.f;
            #pragma unroll
            for (int rf = 0; rf < 3; ++rf)
                #pragma unroll
                for (int rg = 0; rg < 4; ++rg) {
                    float mv = mm[rf][rg];
                    float v = acc[rf][cf][rg];
                    s += mv * v; q += mv * v * v;
                }
            s += __shfl_xor(s, 16, 64); s += __shfl_xor(s, 32, 64);
            q += __shfl_xor(q, 16, 64); q += __shfl_xor(q, 32, 64);
            sacc[cf] += s;      // butterfly leaves total in all lanes
            qacc[cf] += q;
        }
        {
            u32* H = Hbase + (size_t)t * (RPB * 128) + 16 * w + l15;
            #pragma unroll
            for (int rf = 0; rf < 3; ++rf)
                #pragma unroll
                for (int rg = 0; rg < 4; ++rg) {
                    const int row = rf * 16 + l4 * 4 + rg;
                    if (mm[rf][rg] != 0.f)
                        H[(size_t)row * 128] = pkbf(acc[rf][0][rg], acc[rf][1][rg]);
                }
        }

        // ---- pack + write next tile; prefetch meta for tn+GRID1 ----
        if (hasNext) write_tile(D, M, bufn, w, l, tid);
        if (tn + GRID1 < NBLK) {
            load_meta(M, nbridx, mask, (tn + GRID1) * RPB, w, l, tid);
            cnt_acc += M.mrow;
        }
        __syncthreads();   // drains staged loads (issued ~1 K-loop ago) + H stores
        cur ^= 1;
    }

    // ---- end-of-block: fused red1 + mask_cnt (65K atomics total, spread) ----
    if (l4 == 0) {
        #pragma unroll
        for (int cf = 0; cf < 2; ++cf) {
            int col = cf * 128 + 16 * w + l15;
            atomicAdd(&ws[WS_SUM1 + col],   sacc[cf]);
            atomicAdd(&ws[WS_SUMSQ1 + col], qacc[cf]);
        }
    }
    if (w == 0) {   // only wave 0 (tid<48) holds nonzero cnt contributions
        float c = cnt_acc;
        #pragma unroll
        for (int d = 1; d < 64; d <<= 1) c += __shfl_xor(c, d, 64);
        if (l == 0) atomicAdd(&ws[WS_CNT], c);
    }
}

// Fallback path (small workspace): original one-shot kernel, MODE 0 (stats) / MODE 2 (recompute+gate)
template <int MODE>
__global__ __launch_bounds__(256, 3) void gemm_pass(
    const float* __restrict__ atom, const float* __restrict__ nbrf,
    const int* __restrict__ nbridx, const float* __restrict__ mask,
    const u16* __restrict__ wsW, float* __restrict__ ws)
{
    __shared__ __align__(16) char smem[RPB * A_PITCH];   // A-tile; MODE2 reuses as g16
    __shared__ float m_lds[RPB];
    __shared__ int   idx_lds[RPB];
    __shared__ float red[(MODE == 2) ? 4 : 1][128];

    const int tid = threadIdx.x;
    const int w = tid >> 6, l = tid & 63, l15 = l & 15, l4 = l >> 4;
    const int h32 = l >> 5, c32 = l & 31;
    const int blk = blockIdx.x;
    const int r0 = blk * RPB;
    float* __restrict__ P = ws + WS_P_FOFF;

    if (tid < RPB) {
        m_lds[tid] = mask[r0 + tid];
        idx_lds[tid] = nbridx[r0 + tid];
    }
    __syncthreads();

    {
        float4 sv = *(const float4*)(atom + (size_t)(blk * 4 + w) * 128 + c32 * 4);
        uint2 p; p.x = pkbf(sv.x, sv.y); p.y = pkbf(sv.z, sv.w);
        #pragma unroll
        for (int jj = 0; jj < 6; ++jj) {
            int row = 12 * w + 6 * h32 + jj;
            *(uint2*)(smem + row * A_PITCH + c32 * 8) = p;
        }
    }
    {
        float4 v[6]; float mrow[6];
        #pragma unroll
        for (int i = 0; i < 6; ++i) {
            int row = 12 * w + 2 * i + h32;
            mrow[i] = m_lds[row];
            if (mrow[i] != 0.f)
                v[i] = *(const float4*)(atom + (size_t)idx_lds[row] * 128 + c32 * 4);
        }
        #pragma unroll
        for (int i = 0; i < 6; ++i) {
            int row = 12 * w + 2 * i + h32;
            uint2 p; p.x = 0u; p.y = 0u;
            if (mrow[i] != 0.f) { p.x = pkbf(v[i].x, v[i].y); p.y = pkbf(v[i].z, v[i].w); }
            *(uint2*)(smem + row * A_PITCH + 256 + c32 * 8) = p;
        }
    }
    {
        const float* nf = nbrf + (size_t)(r0 + 12 * w) * 64;
        float4 v[3]; float mrow[3]; int rowv[3], cv[3];
        #pragma unroll
        for (int i = 0; i < 3; ++i) {
            int g = i * 64 + l;
            rowv[i] = 12 * w + (g >> 4);
            cv[i] = g & 15;
            mrow[i] = m_lds[rowv[i]];
            if (mrow[i] != 0.f) v[i] = *(const float4*)(nf + g * 4);
        }
        #pragma unroll
        for (int i = 0; i < 3; ++i) {
            uint2 p; p.x = 0u; p.y = 0u;
            if (mrow[i] != 0.f) { p.x = pkbf(v[i].x, v[i].y); p.y = pkbf(v[i].z, v[i].w); }
            *(uint2*)(smem + rowv[i] * A_PITCH + 512 + cv[i] * 8) = p;
        }
    }
    __syncthreads();

    f32x4 acc[3][4];
    #pragma unroll
    for (int rf = 0; rf < 3; rf++)
        #pragma unroll
        for (int cf = 0; cf < 4; cf++)
            acc[rf][cf] = (f32x4){0.f, 0.f, 0.f, 0.f};

    const char* Ab = smem + l15 * A_PITCH + l4 * 16;
    const char* Bb = (const char*)wsW + ((size_t)w * 2048 + l15 * 64 + l4 * 16);
    frag bcur[4], bnext[4];
    #pragma unroll
    for (int cf = 0; cf < 4; ++cf)
        bcur[cf] = *(const frag*)(Bb + cf * 1024 + (cf >= 2 ? 6144 : 0));
    #pragma unroll
    for (int kk = 0; kk < KC; ++kk) {
        if (kk < KC - 1) {
            const char* Bn = Bb + (kk + 1) * 16384;
            #pragma unroll
            for (int cf = 0; cf < 4; ++cf)
                bnext[cf] = *(const frag*)(Bn + cf * 1024 + (cf >= 2 ? 6144 : 0));
        }
        frag a[3];
        #pragma unroll
        for (int rf = 0; rf < 3; rf++)
            a[rf] = *(const frag*)(Ab + rf * 16 * A_PITCH + kk * 64);
        #pragma unroll
        for (int rf = 0; rf < 3; rf++)
            #pragma unroll
            for (int cf = 0; cf < 4; cf++)
                acc[rf][cf] = __builtin_amdgcn_mfma_f32_16x16x32_bf16(a[rf], bcur[cf], acc[rf][cf], 0, 0, 0);
        #pragma unroll
        for (int cf = 0; cf < 4; ++cf) bcur[cf] = bnext[cf];
    }

    if constexpr (MODE == 0) {
        #pragma unroll
        for (int cf = 0; cf < 4; cf++) {
            float s = 0.f, q = 0.f;
            #pragma unroll
            for (int rf = 0; rf < 3; rf++)
                #pragma unroll
                for (int rg = 0; rg < 4; rg++) {
                    int row = rf * 16 + l4 * 4 + rg;
                    float mv = m_lds[row];
                    float v = acc[rf][cf][rg];
                    s += mv * v; q += mv * v * v;
                }
            s += __shfl_xor(s, 16, 64); s += __shfl_xor(s, 32, 64);
            q += __shfl_xor(q, 16, 64); q += __shfl_xor(q, 32, 64);
            if (l4 == 0) {
                int col = w * 32 + cf * 16 + (cf >= 2 ? 96 : 0) + l15;
                P[(size_t)blk * 512 + col]       = s;
                P[(size_t)blk * 512 + 256 + col] = q;
            }
        }
    } else {
        __syncthreads();
        u16* g16 = (u16*)smem;
        #pragma unroll
        for (int cf = 0; cf < 4; cf++) {
            int col = w * 32 + cf * 16 + (cf >= 2 ? 96 : 0) + l15;
            float sc = ws[WS_SCALE1 + col];
            float sh = ws[WS_SHIFT1 + col];
            #pragma unroll
            for (int rf = 0; rf < 3; rf++)
                #pragma unroll
                for (int rg = 0; rg < 4; rg++) {
                    int row = rf * 16 + l4 * 4 + rg;
                    g16[row * 256 + col] = f2bf1(acc[rf][cf][rg] * sc + sh);
                }
        }
        __syncthreads();
        int h = tid >> 7;
        int c = tid & 127;
        float ns0 = 0.f, ns1 = 0.f;
        #pragma unroll
        for (int la2 = 0; la2 < 2; la2++) {
            int la = h * 2 + la2;
            float a_ns = 0.f;
            #pragma unroll
            for (int j = 0; j < 12; j++) {
                int row = la * 12 + j;
                float f = bf2f(g16[row * 256 + c]);
                float k = bf2f(g16[row * 256 + 128 + c]);
                a_ns += m_lds[row] * sigmoidf(f) * softplusf(k);
            }
            ws[WS_NBR + (blk * 4 + la) * 128 + c] = a_ns;
            if (la2 == 0) ns0 = a_ns; else ns1 = a_ns;
        }
        red[h][c]     = ns0 + ns1;
        red[2 + h][c] = ns0 * ns0 + ns1 * ns1;
        __syncthreads();
        if (tid < 128) {
            P[(size_t)blk * 256 + tid]       = red[0][tid] + red[1][tid];
            P[(size_t)blk * 256 + 128 + tid] = red[2][tid] + red[3][tid];
        }
    }
}

// path-A pass 2: thread (h=tid>>6, lane) -> atom la=h, col pair (2*lane, 2*lane+1).
// uint2 H loads: one instr = full 512B row per wave. Inline finalize1.
// P2 partials stored per block (NO global atomics -> round-5 regression reverted).
__global__ __launch_bounds__(256) void pass2_gate(
    const float* __restrict__ ws_ro, const float* __restrict__ mask,
    const float* __restrict__ g1, const float* __restrict__ b1,
    float* __restrict__ ws)
{
    __shared__ float m_lds[RPB];
    __shared__ float redS[4][128];
    __shared__ float redQ[4][128];

    const int tid = threadIdx.x;
    const int blk = blockIdx.x;
    const int h = tid >> 6;          // atom la = h (0..3)
    const int lane = tid & 63;
    const int c0 = 2 * lane, c1 = 2 * lane + 1;
    float* __restrict__ P = ws + WS_P_FOFF;

    if (tid < RPB) m_lds[tid] = mask[blk * RPB + tid];

    // inline finalize1 (SUM1/SUMSQ1/CNT complete after gemm1_pipe; all L2-hot)
    const float rc = 1.f / ws_ro[WS_CNT];
    float scf0, shf0, sck0, shk0, scf1, shf1, sck1, shk1;
    {
        float m = ws_ro[WS_SUM1 + c0] * rc;
        float v = ws_ro[WS_SUMSQ1 + c0] * rc - m * m;
        scf0 = g1[c0] * rsqrtf(v + EPSV); shf0 = b1[c0] - m * scf0;
    }
    {
        float m = ws_ro[WS_SUM1 + 128 + c0] * rc;
        float v = ws_ro[WS_SUMSQ1 + 128 + c0] * rc - m * m;
        sck0 = g1[128 + c0] * rsqrtf(v + EPSV); shk0 = b1[128 + c0] - m * sck0;
    }
    {
        float m = ws_ro[WS_SUM1 + c1] * rc;
        float v = ws_ro[WS_SUMSQ1 + c1] * rc - m * m;
        scf1 = g1[c1] * rsqrtf(v + EPSV); shf1 = b1[c1] - m * scf1;
    }
    {
        float m = ws_ro[WS_SUM1 + 128 + c1] * rc;
        float v = ws_ro[WS_SUMSQ1 + 128 + c1] * rc - m * m;
        sck1 = g1[128 + c1] * rsqrtf(v + EPSV); shk1 = b1[128 + c1] - m * sck1;
    }
    __syncthreads();

    // H row base for atom h: rows h*12 .. h*12+11
    const uint2* Hb = (const uint2*)((const u32*)(ws_ro + WS_G_FOFF)
                        + (size_t)blk * (RPB * 128) + (size_t)(h * 12) * 128) + lane;

    uint2 v[12]; float mv[12];
    #pragma unroll
    for (int j = 0; j < 12; j++) {
        mv[j] = m_lds[h * 12 + j];                 // wave-uniform
        if (mv[j] != 0.f) v[j] = Hb[j * 64];
    }
    float ns0 = 0.f, ns1 = 0.f;
    #pragma unroll
    for (int j = 0; j < 12; j++) {
        if (mv[j] != 0.f) {
            u32 ux = v[j].x, uy = v[j].y;
            float f0 = bits2f(ux << 16)          * scf0 + shf0;
            float k0 = bits2f(ux & 0xffff0000u)  * sck0 + shk0;
            float f1 = bits2f(uy << 16)          * scf1 + shf1;
            float k1 = bits2f(uy & 0xffff0000u)  * sck1 + shk1;
            ns0 += __builtin_amdgcn_rcpf(1.f + __expf(-f0)) *
                   (fmaxf(k0, 0.f) + __logf(1.f + __expf(-fabsf(k0))));
            ns1 += __builtin_amdgcn_rcpf(1.f + __expf(-f1)) *
                   (fmaxf(k1, 0.f) + __logf(1.f + __expf(-fabsf(k1))));
        }
    }
    // coalesced float2 NBR write
    {
        float2 o; o.x = ns0; o.y = ns1;
        *(float2*)(ws + WS_NBR + (size_t)(blk * 4 + h) * 128 + c0) = o;
    }
    redS[h][c0] = ns0; redS[h][c1] = ns1;
    redQ[h][c0] = ns0 * ns0; redQ[h][c1] = ns1 * ns1;
    __syncthreads();
    if (tid < 128) {
        P[(size_t)blk * 256 + tid]       = redS[0][tid] + redS[1][tid] + redS[2][tid] + redS[3][tid];
        P[(size_t)blk * 256 + 128 + tid] = redQ[0][tid] + redQ[1][tid] + redQ[2][tid] + redQ[3][tid];
    }
}

// reduce P1[12500][512] over blocks -> ws[WS_SUM1..] ; grid 250 (fallback path)
__global__ __launch_bounds__(256) void red1(const float* __restrict__ ws_ro, float* __restrict__ ws) {
    const float* P = ws_ro + WS_P_FOFF;
    int c = (blockIdx.x & 1) * 256 + threadIdx.x;
    int s = blockIdx.x >> 1;
    const float* p = P + (size_t)s * 100 * 512 + c;
    float a = 0.f;
    #pragma unroll 4
    for (int r = 0; r < 100; r++) a += p[(size_t)r * 512];
    atomicAdd(&ws[WS_SUM1 + c], a);
}

// reduce P2[12500][256] over blocks -> ws[WS_SUM2..] ; grid 125 (both paths)
__global__ __launch_bounds__(256) void red2(const float* __restrict__ ws_ro, float* __restrict__ ws) {
    const float* P = ws_ro + WS_P_FOFF;
    int s = blockIdx.x;
    const float* p = P + (size_t)s * 100 * 256 + threadIdx.x;
    float a = 0.f;
    #pragma unroll 4
    for (int r = 0; r < 100; r++) a += p[(size_t)r * 256];
    atomicAdd(&ws[WS_SUM2 + threadIdx.x], a);
}

// fallback path only (bigws inlines this into pass2_gate)
__global__ void finalize1(float* __restrict__ ws, const float* __restrict__ g1, const float* __restrict__ b1) {
    int c = threadIdx.x;  // 256
    float cnt = ws[WS_CNT];
    float mean = ws[WS_SUM1 + c] / cnt;
    float var  = ws[WS_SUMSQ1 + c] / cnt - mean * mean;
    float sc = g1[c] * rsqrtf(var + EPSV);
    ws[WS_SCALE1 + c] = sc;
    ws[WS_SHIFT1 + c] = b1[c] - mean * sc;
}

// out_kernel with inline finalize2 (both paths)
__global__ __launch_bounds__(256) void out_kernel(
    const float* __restrict__ atom, const float* __restrict__ ws,
    const float* __restrict__ g2, const float* __restrict__ b2,
    float* __restrict__ out)
{
    int g = blockIdx.x * 256 + threadIdx.x;
    if (g >= N_ATOM * 32) return;
    int i = g >> 5, c4 = (g & 31) * 4;
    const float inv = 1.f / (float)N_ATOM;
    float4 s2  = *(const float4*)(ws + WS_SUM2 + c4);
    float4 q2  = *(const float4*)(ws + WS_SUMSQ2 + c4);
    float4 g2v = *(const float4*)(g2 + c4);
    float4 b2v = *(const float4*)(b2 + c4);
    float4 sc, sh;
    { float m = s2.x * inv; sc.x = g2v.x * rsqrtf(q2.x * inv - m * m + EPSV); sh.x = b2v.x - m * sc.x; }
    { float m = s2.y * inv; sc.y = g2v.y * rsqrtf(q2.y * inv - m * m + EPSV); sh.y = b2v.y - m * sc.y; }
    { float m = s2.z * inv; sc.z = g2v.z * rsqrtf(q2.z * inv - m * m + EPSV); sh.z = b2v.z - m * sc.z; }
    { float m = s2.w * inv; sc.w = g2v.w * rsqrtf(q2.w * inv - m * m + EPSV); sh.w = b2v.w - m * sc.w; }
    float4 av = *(const float4*)(atom + i * 128 + c4);
    float4 nv = *(const float4*)(ws + WS_NBR + i * 128 + c4);
    float4 ov;
    ov.x = softplusf(av.x + nv.x * sc.x + sh.x);
    ov.y = softplusf(av.y + nv.y * sc.y + sh.y);
    ov.z = softplusf(av.z + nv.z * sc.z + sh.z);
    ov.w = softplusf(av.w + nv.w * sc.w + sh.w);
    *(float4*)(out + i * 128 + c4) = ov;
}

extern "C" void kernel_launch(void* const* d_in, const int* in_sizes, int n_in,
                              void* d_out, int out_size, void* d_ws, size_t ws_size,
                              hipStream_t stream) {
    (void)in_sizes; (void)n_in; (void)out_size;
    const float* atom = (const float*)d_in[0];
    const float* nbrf = (const float*)d_in[1];
    const int*   nidx = (const int*)d_in[2];
    const float* mask = (const float*)d_in[3];
    const float* W    = (const float*)d_in[4];
    // d_in[5] = b_fc: zeros AND cancels exactly through BN1 for masked rows; unused
    const float* g1 = (const float*)d_in[6];
    const float* b1 = (const float*)d_in[7];
    const float* g2 = (const float*)d_in[8];
    const float* b2 = (const float*)d_in[9];
    float* ws  = (float*)d_ws;
    u16*  wsW  = (u16*)((char*)d_ws + (size_t)WS_W_FOFF * 4);
    float* out = (float*)d_out;
    const bool bigws = (ws_size >= WS_NEED_BYTES);

    hipMemsetAsync(d_ws, 0, WS_STATS_END * 4, stream);
    swizzleW<<<(KDIM * CDIM + 255) / 256, 256, 0, stream>>>(W, wsW);
    if (bigws) {
        gemm1_pipe<<<GRID1, 512, 0, stream>>>(atom, nbrf, nidx, mask, wsW, ws);
        pass2_gate<<<NBLK, 256, 0, stream>>>(ws, mask, g1, b1, ws);
        red2<<<125, 256, 0, stream>>>(ws, ws);
    } else {
        mask_cnt<<<147, 256, 0, stream>>>(mask, ws);
        gemm_pass<0><<<NBLK, 256, 0, stream>>>(atom, nbrf, nidx, mask, wsW, ws);
        red1<<<250, 256, 0, stream>>>(ws, ws);
        finalize1<<<1, 256, 0, stream>>>(ws, g1, b1);
        gemm_pass<2><<<NBLK, 256, 0, stream>>>(atom, nbrf, nidx, mask, wsW, ws);
        red2<<<125, 256, 0, stream>>>(ws, ws);
    }
    out_kernel<<<(N_ATOM * 32 + 255) / 256, 256, 0, stream>>>(atom, ws, g2, b2, out);
}